// Round 11
// baseline (288.267 us; speedup 1.0000x reference)
//
#include <hip/hip_runtime.h>
#include <hip/hip_bf16.h>
#include <math.h>

#define N_   1024
#define S_   256
#define D_   256
#define C_   256
#define R_   64
#define CLS_ 1000
#define INV16 0.0625f

typedef unsigned short ushortT;
typedef unsigned int uint32;
typedef short bf8 __attribute__((ext_vector_type(8)));
typedef float f4 __attribute__((ext_vector_type(4)));

static __device__ __forceinline__ float bf2f(uint32 u){
  return __uint_as_float(u << 16);
}
static __device__ __forceinline__ ushortT f2bf(float f){
  uint32 x = __float_as_uint(f);
  uint32 r = x + 0x7FFFu + ((x >> 16) & 1u);
  return (ushortT)(r >> 16);
}
static __device__ __forceinline__ uint32 packbf(float a, float b){
  return ((uint32)f2bf(b) << 16) | (uint32)f2bf(a);
}
static __device__ __forceinline__ float wred_max(float v){
  for (int o = 32; o; o >>= 1) v = fmaxf(v, __shfl_xor(v, o));
  return v;
}
static __device__ __forceinline__ float wred_sum(float v){
  for (int o = 32; o; o >>= 1) v += __shfl_xor(v, o);
  return v;
}
// swizzled byte offset inside a [rows][256]-bf16 LDS tile (row stride 512B)
static __device__ __forceinline__ int swz(int row, int colbyte){
  return row*512 + ((colbyte & ~15) ^ ((row & 7) << 4)) + (colbyte & 15);
}
// fragment-ready packed index for a [rows x 256] matrix, 16-row frags, K-step 32
static __device__ __forceinline__ int pkidx(int row, int col, int nfrag){
  int ks = col >> 5, hi = (col >> 3) & 3, e = col & 7;
  int frag = row >> 4, l15p = row & 15;
  return ((ks*nfrag + frag)*64 + hi*16 + l15p)*8 + e;
}

// ---------------- K0: weight prep + MT = cb @ rcb^T + sum_ws zero -------------
__global__ __launch_bounds__(256) void k0(const float* __restrict__ cb,
    const float* __restrict__ rcb, const float* __restrict__ Wc,
    const float* __restrict__ Wr, ushortT* __restrict__ a1pk,
    ushortT* __restrict__ Wcr_bf, float* __restrict__ MT_f32,
    ushortT* __restrict__ mtpk, float* __restrict__ sum_ws)
{
  __shared__ float rl[D_];
  int bid = blockIdx.x, t = threadIdx.x;
  int gtid = bid*256 + t;
  int stride = gridDim.x*256;
  for (int e = gtid; e < (C_ + R_)*D_; e += stride){
    int row = e >> 8, col = e & 255;
    float v = (row < C_) ? cb[e] : rcb[e - C_*D_];
    a1pk[pkidx(row, col, 20)] = f2bf(v);
  }
  for (int e = gtid; e < CLS_*D_; e += stride) Wcr_bf[e] = f2bf(Wc[e]);
  for (int e = gtid; e < D_*D_; e += stride)  Wcr_bf[CLS_*D_ + e] = f2bf(Wr[e]);
  for (int e = gtid; e < 24*D_; e += stride)  Wcr_bf[1256*D_ + e] = 0;
  for (int e = gtid; e < N_*D_; e += stride)  sum_ws[e] = 0.f;

  if (bid < R_){
    rl[t] = rcb[bid*D_ + t];
    __syncthreads();
    float acc = 0.f;
    const float* crow = cb + t*D_;
    #pragma unroll 8
    for (int k = 0; k < D_; k += 4){
      float4 w = *(const float4*)(crow + k);
      acc += w.x*rl[k] + w.y*rl[k+1] + w.z*rl[k+2] + w.w*rl[k+3];
    }
    MT_f32[bid*C_ + t] = acc;
    mtpk[pkidx(bid, t, 4)] = f2bf(acc);
  }
}

// ---------------- K1: per-query pass, batched x4 ------------------------------
#define G4 4
__global__ __launch_bounds__(256) void k1(const float* __restrict__ q,
    const float* __restrict__ cb, const float* __restrict__ rcb,
    const float* __restrict__ Wq, const float* __restrict__ MT_f32,
    float* __restrict__ cw_ws, float* __restrict__ rcw_ws)
{
  __shared__ float qv[G4][D_], qp[G4][D_], cwl[G4][C_];
  __shared__ float redA[G4][4], redB2[G4][4];
  int n0 = blockIdx.x*G4, t = threadIdx.x;
  #pragma unroll
  for (int g = 0; g < G4; g++) qv[g][t] = q[(n0+g)*D_ + t];
  __syncthreads();
  {
    float acc[G4] = {0.f,0.f,0.f,0.f};
    const float* wrow = Wq + t*D_;
    #pragma unroll 4
    for (int k = 0; k < D_; k += 4){
      float4 w = *(const float4*)(wrow + k);
      #pragma unroll
      for (int g = 0; g < G4; g++)
        acc[g] += qv[g][k]*w.x + qv[g][k+1]*w.y + qv[g][k+2]*w.z + qv[g][k+3]*w.w;
    }
    #pragma unroll
    for (int g = 0; g < G4; g++) qp[g][t] = acc[g];
  }
  __syncthreads();
  float L[G4] = {0.f,0.f,0.f,0.f};
  {
    const float* crow = cb + t*D_;
    #pragma unroll 4
    for (int k = 0; k < D_; k += 4){
      float4 w = *(const float4*)(crow + k);
      #pragma unroll
      for (int g = 0; g < G4; g++)
        L[g] += qp[g][k]*w.x + qp[g][k+1]*w.y + qp[g][k+2]*w.z + qp[g][k+3]*w.w;
    }
  }
  float m[G4], e[G4], s[G4];
  #pragma unroll
  for (int g = 0; g < G4; g++){ L[g] *= INV16; m[g] = wred_max(L[g]); }
  if ((t & 63) == 0)
    #pragma unroll
    for (int g = 0; g < G4; g++) redA[g][t >> 6] = m[g];
  __syncthreads();
  #pragma unroll
  for (int g = 0; g < G4; g++){
    m[g] = fmaxf(fmaxf(redA[g][0], redA[g][1]), fmaxf(redA[g][2], redA[g][3]));
    e[g] = __expf(L[g] - m[g]);
    s[g] = wred_sum(e[g]);
  }
  if ((t & 63) == 0)
    #pragma unroll
    for (int g = 0; g < G4; g++) redB2[g][t >> 6] = s[g];
  __syncthreads();
  #pragma unroll
  for (int g = 0; g < G4; g++){
    float ss = redB2[g][0] + redB2[g][1] + redB2[g][2] + redB2[g][3];
    float w = e[g] / ss;
    cwl[g][t] = w;
    cw_ws[(n0+g)*C_ + t] = w;
  }
  __syncthreads();
  if (t < R_){
    float qd[G4] = {0.f,0.f,0.f,0.f}, md[G4] = {0.f,0.f,0.f,0.f};
    const float* rrow = rcb + t*D_;
    const float* mrow = MT_f32 + t*C_;
    #pragma unroll 4
    for (int k = 0; k < D_; k += 4){
      float4 wv = *(const float4*)(rrow + k);
      float4 mv = *(const float4*)(mrow + k);
      #pragma unroll
      for (int g = 0; g < G4; g++){
        qd[g] += qp[g][k]*wv.x + qp[g][k+1]*wv.y + qp[g][k+2]*wv.z + qp[g][k+3]*wv.w;
        md[g] += cwl[g][k]*mv.x + cwl[g][k+1]*mv.y + cwl[g][k+2]*mv.z + cwl[g][k+3]*mv.w;
      }
    }
    #pragma unroll
    for (int g = 0; g < G4; g++){
      float Lr = (qd[g] - md[g]) * INV16;
      float mr = wred_max(Lr);
      float er = __expf(Lr - mr);
      float sr = wred_sum(er);
      rcw_ws[(n0+g)*R_ + t] = er / sr;
    }
  }
}

// ---------------- K2a: fused weights + summary pass (4 barriers) --------------
// block = (n, 64-s tile); 4 waves. Wave w owns: c-frags {w+4f} (GEMM1-C),
// r-frag (16+w) across ALL s (GEMM1-R), MT-frag w (WM), s-quarter w (comb+V).
__global__ __launch_bounds__(256) void k2a(const float* __restrict__ Kt,
    const float* __restrict__ Vt, const ushortT* __restrict__ a1pk,
    const ushortT* __restrict__ mtpk, const float* __restrict__ cw_ws,
    const float* __restrict__ rcw_ws, const float* __restrict__ rlogit,
    float* __restrict__ sum_ws, float* __restrict__ out_ew)
{
  __shared__ __align__(16) ushortT KW[64*256];   // 32 KB: Ktile, then Wexp overlay
  __shared__ float redS[4][64], redW[4][64];

  int bx  = blockIdx.x;
  int n   = bx >> 2;
  int s0  = (bx & 3) * 64;
  int tid = threadIdx.x;
  int lane = tid & 63, w = tid >> 6;
  int l15 = lane & 15, l4 = lane >> 4;
  float gate  = 1.f / (1.f + __expf(-rlogit[0]));
  float inv1g = 1.f / (1.f + gate);

  const float* Kn = Kt + (size_t)n*S_*D_ + (size_t)s0*D_;

  // ---- preload bnxR (r-frag 16+w, all 8 ks): L2, consumed in GEMM1 ----------
  const ushortT* aRb = a1pk + (size_t)((16 + w)*64 + lane)*8;
  bf8 bR[8];
  #pragma unroll
  for (int ks = 0; ks < 8; ks++)
    bR[ks] = *(const bf8*)(aRb + (size_t)(ks*20*64)*8);

  // ---- stage K tile fp32 -> bf16 swz LDS ----
  #pragma unroll
  for (int j = 0; j < 8; j++){
    int ch = tid + j*256;
    int row = ch >> 5, blk = ch & 31;
    const float* src = Kn + row*D_ + blk*8;
    float4 a = *(const float4*)src;
    float4 b = *(const float4*)(src + 4);
    uint4 wv = {packbf(a.x,a.y), packbf(a.z,a.w), packbf(b.x,b.y), packbf(b.z,b.w)};
    *(uint4*)((char*)KW + swz(row, blk*16)) = wv;
  }
  __syncthreads();                                   // B1

  // ---- GEMM1: accC[4 cf][4 sj] + accR[4 sj] (r-frag 16+w) -------------------
  const ushortT* a1b = a1pk + (size_t)lane*8;
  bf8 bnxC[4];
  #pragma unroll
  for (int f = 0; f < 4; f++)
    bnxC[f] = *(const bf8*)(a1b + (size_t)((w + 4*f)*64)*8);
  f4 accC[4][4]; f4 accR[4];
  #pragma unroll
  for (int f = 0; f < 4; f++){
    accR[f] = (f4)0.f;
    #pragma unroll
    for (int sj = 0; sj < 4; sj++) accC[f][sj] = (f4)0.f;
  }
  #pragma unroll
  for (int ks = 0; ks < 8; ks++){
    bf8 kf0 = *(const bf8*)((const char*)KW + swz(     l15, ks*64 + l4*16));
    bf8 kf1 = *(const bf8*)((const char*)KW + swz(16 + l15, ks*64 + l4*16));
    bf8 kf2 = *(const bf8*)((const char*)KW + swz(32 + l15, ks*64 + l4*16));
    bf8 kf3 = *(const bf8*)((const char*)KW + swz(48 + l15, ks*64 + l4*16));
    #pragma unroll
    for (int f = 0; f < 4; f++){
      bf8 aC = bnxC[f];
      if (ks < 7)
        bnxC[f] = *(const bf8*)(a1b + (size_t)(((ks+1)*20 + w + 4*f)*64)*8);
      accC[f][0] = __builtin_amdgcn_mfma_f32_16x16x32_bf16(aC, kf0, accC[f][0], 0, 0, 0);
      accC[f][1] = __builtin_amdgcn_mfma_f32_16x16x32_bf16(aC, kf1, accC[f][1], 0, 0, 0);
      accC[f][2] = __builtin_amdgcn_mfma_f32_16x16x32_bf16(aC, kf2, accC[f][2], 0, 0, 0);
      accC[f][3] = __builtin_amdgcn_mfma_f32_16x16x32_bf16(aC, kf3, accC[f][3], 0, 0, 0);
    }
    accR[0] = __builtin_amdgcn_mfma_f32_16x16x32_bf16(bR[ks], kf0, accR[0], 0, 0, 0);
    accR[1] = __builtin_amdgcn_mfma_f32_16x16x32_bf16(bR[ks], kf1, accR[1], 0, 0, 0);
    accR[2] = __builtin_amdgcn_mfma_f32_16x16x32_bf16(bR[ks], kf2, accR[2], 0, 0, 0);
    accR[3] = __builtin_amdgcn_mfma_f32_16x16x32_bf16(bR[ks], kf3, accR[3], 0, 0, 0);
  }

  // ---- preload mnx (MT-frag w, all 8 ks): L2, consumed in WM ----------------
  const ushortT* mtb = mtpk + (size_t)(w*64 + lane)*8;
  bf8 mnx[8];
  #pragma unroll
  for (int ks = 0; ks < 8; ks++)
    mnx[ks] = *(const bf8*)(mtb + (size_t)(ks*4*64)*8);

  // ---- softmax-c partials (exp in place, unnormalized) ----------------------
  float4 cwv[4];
  #pragma unroll
  for (int f = 0; f < 4; f++)
    cwv[f] = *(const float4*)(cw_ws + n*C_ + (w + 4*f)*16 + l4*4);
  float se[4] = {0,0,0,0}, sb[4] = {0,0,0,0};
  #pragma unroll
  for (int f = 0; f < 4; f++)
    #pragma unroll
    for (int sj = 0; sj < 4; sj++){
      float e0 = __expf(accC[f][sj][0] * INV16);
      float e1 = __expf(accC[f][sj][1] * INV16);
      float e2 = __expf(accC[f][sj][2] * INV16);
      float e3 = __expf(accC[f][sj][3] * INV16);
      accC[f][sj][0] = e0; accC[f][sj][1] = e1;
      accC[f][sj][2] = e2; accC[f][sj][3] = e3;
      se[sj] += (e0 + e1) + (e2 + e3);
      sb[sj] += e0*cwv[f].x + e1*cwv[f].y + e2*cwv[f].z + e3*cwv[f].w;
    }
  #pragma unroll
  for (int sj = 0; sj < 4; sj++){
    se[sj] += __shfl_xor(se[sj], 16); se[sj] += __shfl_xor(se[sj], 32);
    sb[sj] += __shfl_xor(sb[sj], 16); sb[sj] += __shfl_xor(sb[sj], 32);
  }
  if (l4 == 0){
    #pragma unroll
    for (int sj = 0; sj < 4; sj++){
      redS[w][sj*16 + l15] = se[sj];
      redW[w][sj*16 + l15] = sb[sj];
    }
  }
  __syncthreads();                                   // B2 (K reads done)

  float rcp[4];                       // 1/sum_e for s-col (sj*16+l15), all sj
  #pragma unroll
  for (int sj = 0; sj < 4; sj++){
    int s_ = sj*16 + l15;
    rcp[sj] = 1.f / (redS[0][s_] + redS[1][s_] + redS[2][s_] + redS[3][s_]);
  }
  float bw_q;                         // base weight for own s-quarter (s = w*16+l15)
  {
    int sq = w*16 + l15;
    float sS = redS[0][sq] + redS[1][sq] + redS[2][sq] + redS[3][sq];
    float sW = redW[0][sq] + redW[1][sq] + redW[2][sq] + redW[3][sq];
    bw_q = sW / sS;
  }
  // ---- Wexp (unnormalized, bf16) overlays Ktile ----
  #pragma unroll
  for (int f = 0; f < 4; f++){
    int cbyte = ((w + 4*f)*16 + l4*4) * 2;
    #pragma unroll
    for (int sj = 0; sj < 4; sj++){
      int s_ = sj*16 + l15;
      *(uint32*)((char*)KW + swz(s_, cbyte))     = packbf(accC[f][sj][0], accC[f][sj][1]);
      *(uint32*)((char*)KW + swz(s_, cbyte + 4)) = packbf(accC[f][sj][2], accC[f][sj][3]);
    }
  }
  __syncthreads();                                   // B3

  // ---- WM: MT-frag w x Wexp^T -> wm[4 sj] -----------------------------------
  f4 wm[4];
  #pragma unroll
  for (int sj = 0; sj < 4; sj++) wm[sj] = (f4)0.f;
  #pragma unroll
  for (int ks = 0; ks < 8; ks++){
    bf8 wb0 = *(const bf8*)((const char*)KW + swz(     l15, ks*64 + l4*16));
    bf8 wb1 = *(const bf8*)((const char*)KW + swz(16 + l15, ks*64 + l4*16));
    bf8 wb2 = *(const bf8*)((const char*)KW + swz(32 + l15, ks*64 + l4*16));
    bf8 wb3 = *(const bf8*)((const char*)KW + swz(48 + l15, ks*64 + l4*16));
    wm[0] = __builtin_amdgcn_mfma_f32_16x16x32_bf16(mnx[ks], wb0, wm[0], 0, 0, 0);
    wm[1] = __builtin_amdgcn_mfma_f32_16x16x32_bf16(mnx[ks], wb1, wm[1], 0, 0, 0);
    wm[2] = __builtin_amdgcn_mfma_f32_16x16x32_bf16(mnx[ks], wb2, wm[2], 0, 0, 0);
    wm[3] = __builtin_amdgcn_mfma_f32_16x16x32_bf16(mnx[ks], wb3, wm[3], 0, 0, 0);
  }

  // ---- r-softmax partials: rows of r-frag (16+w == MT-frag w) ---------------
  float4 rcwv = *(const float4*)(rcw_ws + n*R_ + w*16 + l4*4);
  float se3[4], sc3[4];
  #pragma unroll
  for (int sj = 0; sj < 4; sj++){
    float e0 = __expf((accR[sj][0] - wm[sj][0]*rcp[sj]) * INV16);
    float e1 = __expf((accR[sj][1] - wm[sj][1]*rcp[sj]) * INV16);
    float e2 = __expf((accR[sj][2] - wm[sj][2]*rcp[sj]) * INV16);
    float e3 = __expf((accR[sj][3] - wm[sj][3]*rcp[sj]) * INV16);
    float s_e = (e0 + e1) + (e2 + e3);
    float s_c = e0*rcwv.x + e1*rcwv.y + e2*rcwv.z + e3*rcwv.w;
    s_e += __shfl_xor(s_e, 16); s_e += __shfl_xor(s_e, 32);
    s_c += __shfl_xor(s_c, 16); s_c += __shfl_xor(s_c, 32);
    se3[sj] = s_e; sc3[sj] = s_c;
  }
  if (l4 == 0){
    #pragma unroll
    for (int sj = 0; sj < 4; sj++){
      redS[w][sj*16 + l15] = se3[sj];
      redW[w][sj*16 + l15] = sc3[sj];
    }
  }
  __syncthreads();                                   // B4

  float comb;
  {
    int sq = w*16 + l15;
    float sS = redS[0][sq] + redS[1][sq] + redS[2][sq] + redS[3][sq];
    float sW = redW[0][sq] + redW[1][sq] + redW[2][sq] + redW[3][sq];
    comb = bw_q + gate * (sW / sS);
    if (l4 == 0) out_ew[n*S_ + s0 + sq] = comb * inv1g;
  }

  // ---- fused V summary: wave w handles s-rows [w*16,+16) --------------------
  {
    const float* vp = Vt + (size_t)n*S_*D_ + (size_t)(s0 + w*16)*D_ + lane*4;
    float4 sacc = {0.f, 0.f, 0.f, 0.f};
    #pragma unroll
    for (int j = 0; j < 16; j++){
      float cj = __shfl(comb, j);          // lane j (l4==0 group) holds row w*16+j
      float4 v = *(const float4*)(vp + (size_t)j*D_);
      sacc.x = fmaf(cj, v.x, sacc.x); sacc.y = fmaf(cj, v.y, sacc.y);
      sacc.z = fmaf(cj, v.z, sacc.z); sacc.w = fmaf(cj, v.w, sacc.w);
    }
    float* dst = sum_ws + (size_t)n*D_ + lane*4;
    atomicAdd(dst + 0, sacc.x);
    atomicAdd(dst + 1, sacc.y);
    atomicAdd(dst + 2, sacc.z);
    atomicAdd(dst + 3, sacc.w);
  }
}

// ---------------- K3: readout GEMM (MFMA, bf16) --------------------------------
__global__ __launch_bounds__(256) void k3(const float* __restrict__ sum_ws,
    const ushortT* __restrict__ Wcr_bf, const float* __restrict__ bc,
    const float* __restrict__ br, float* __restrict__ out)
{
  __shared__ __align__(16) ushortT Stile[64*256];
  int bx = blockIdx.x;
  int ot = bx >> 4;
  int nt = bx & 15;
  int tid = threadIdx.x;
  int lane = tid & 63, wid = tid >> 6;
  int l15 = lane & 15, l4 = lane >> 4;

  const float* Sp = sum_ws + (size_t)nt*64*D_;
  #pragma unroll
  for (int j = 0; j < 8; j++){
    int ch = tid + j*256;
    int row = ch >> 5, blk = ch & 31;
    const float* src = Sp + row*D_ + blk*8;
    float4 a = *(const float4*)src;
    float4 b = *(const float4*)(src + 4);
    uint4 wv = {packbf(a.x,a.y), packbf(a.z,a.w), packbf(b.x,b.y), packbf(b.z,b.w)};
    *(uint4*)((char*)Stile + swz(row, blk*16)) = wv;
  }
  __syncthreads();

  int o0 = ot*64 + wid*16;
  const ushortT* Ap = Wcr_bf + (size_t)(o0 + l15)*D_ + l4*8;
  f4 acc[4];
  #pragma unroll
  for (int j = 0; j < 4; j++) acc[j] = (f4)0.f;
  #pragma unroll
  for (int k = 0; k < 8; k++){
    bf8 a = *(const bf8*)(Ap + k*32);
    #pragma unroll
    for (int nj = 0; nj < 4; nj++){
      bf8 b = *(const bf8*)((const char*)Stile + swz(nj*16 + l15, k*64 + l4*16));
      acc[nj] = __builtin_amdgcn_mfma_f32_16x16x32_bf16(a, b, acc[nj], 0, 0, 0);
    }
  }
  int obase = o0 + l4*4;
  if (obase < 1256){
    float4 bias;
    if (obase < CLS_) bias = *(const float4*)(bc + obase);
    else              bias = *(const float4*)(br + (obase - CLS_));
    #pragma unroll
    for (int nj = 0; nj < 4; nj++){
      int nn = nt*64 + nj*16 + l15;
      float4 v = {acc[nj][0]+bias.x, acc[nj][1]+bias.y, acc[nj][2]+bias.z, acc[nj][3]+bias.w};
      if (obase < CLS_) *(float4*)(out + (size_t)nn*CLS_ + obase) = v;
      else              *(float4*)(out + (size_t)N_*CLS_ + (size_t)nn*D_ + (obase - CLS_)) = v;
    }
  }
}

extern "C" void kernel_launch(void* const* d_in, const int* in_sizes, int n_in,
                              void* d_out, int out_size, void* d_ws, size_t ws_size,
                              hipStream_t stream)
{
  const float* q    = (const float*)d_in[0];
  const float* Kt   = (const float*)d_in[1];
  const float* Vt   = (const float*)d_in[2];
  const float* cb   = (const float*)d_in[3];
  const float* rcb  = (const float*)d_in[4];
  const float* Wq   = (const float*)d_in[5];
  const float* rlg  = (const float*)d_in[6];
  const float* Wc   = (const float*)d_in[7];
  const float* bc   = (const float*)d_in[8];
  const float* Wr   = (const float*)d_in[9];
  const float* br   = (const float*)d_in[10];
  float* out = (float*)d_out;
  float* ws  = (float*)d_ws;

  float* cw_ws   = ws;                          // N*C
  float* rcw_ws  = ws + 262144;                 // N*R
  float* sum_ws  = ws + 327680;                 // N*D
  float* MT_f32  = ws + 589824;                 // R*C
  ushortT* a1pk   = (ushortT*)(ws + 606208);    // 320*D frag-packed
  ushortT* mtpk   = a1pk + (C_ + R_)*D_;        // R*C frag-packed
  ushortT* Wcr_bf = mtpk + R_*C_;               // 1280*D (Wc ; Wr ; zero pad)

  float* out_logits = out;
  float* out_ew     = out + (size_t)N_*CLS_ + (size_t)N_*D_;

  k0 <<<128,   256, 0, stream>>>(cb, rcb, Wc, Wr, a1pk, Wcr_bf, MT_f32, mtpk, sum_ws);
  k1 <<<N_/G4, 256, 0, stream>>>(q, cb, rcb, Wq, MT_f32, cw_ws, rcw_ws);
  k2a<<<N_*4,  256, 0, stream>>>(Kt, Vt, a1pk, mtpk, cw_ws, rcw_ws, rlg, sum_ws, out_ew);
  k3 <<<320,   256, 0, stream>>>(sum_ws, Wcr_bf, bc, br, out_logits);
}